// Round 1
// baseline (205.457 us; speedup 1.0000x reference)
//
#include <hip/hip_runtime.h>
#include <math.h>

// loss = mean_b[ 0.5*nrmse(o1,t1) + 0.25*nrmse(o2,t2) + 0.25*nrmse(o3,t3) ]
// B=4096 rows, N=2048 fp32. Memory-bound: 201.3 MB in, 4 B out.
// Roofline: ~32 us at 6.3 TB/s.
constexpr int N_ELEM = 2048;
constexpr int BATCH  = 4096;
constexpr int BLOCK  = 256;                   // 4 waves/block
constexpr int TASKS  = 3 * BATCH;             // 12288 (pair,row) tasks
constexpr int GRID1  = TASKS / (BLOCK / 64);  // 3072 blocks, exactly 1 task/wave

// Stage 1: ONE wave per (pair,row) task — fine-grained, self-balancing
// regardless of how many blocks/CU the VGPR count actually allows.
// 64 lanes x 8 float4 per array = 16 independent 16B loads in flight/lane.
// No atomics; per-block partial to d_ws.
__global__ __launch_bounds__(BLOCK)
void wnrmse_stage1(const float* __restrict__ o1, const float* __restrict__ t1,
                   const float* __restrict__ o2, const float* __restrict__ t2,
                   const float* __restrict__ o3, const float* __restrict__ t3,
                   float* __restrict__ partial)
{
    const int tid  = threadIdx.x;
    const int wave = tid >> 6;
    const int lane = tid & 63;
    const int task = blockIdx.x * (BLOCK / 64) + wave;   // global wave id == task

    const int pair = task >> 12;          // task / 4096   (wave-uniform)
    const int row  = task & (BATCH - 1);  // task % 4096

    // Wave-uniform branchless pointer select -> scalar cselect, no scratch array.
    const float* ob = (pair == 0) ? o1 : ((pair == 1) ? o2 : o3);
    const float* tb = (pair == 0) ? t1 : ((pair == 1) ? t2 : t3);
    const float  wgt = (pair == 0) ? 0.50f : 0.25f;

    const float4* o4 = (const float4*)(ob + (size_t)row * N_ELEM);
    const float4* t4 = (const float4*)(tb + (size_t)row * N_ELEM);

    // Split accumulators to shorten dependency chains.
    float ssd0 = 0.0f, ssd1 = 0.0f;
    float tmax0 = -INFINITY, tmax1 = -INFINITY;
    float tmin0 =  INFINITY, tmin1 =  INFINITY;

    // 512 float4 per row / 64 lanes = 8 per lane, fully coalesced.
#pragma unroll
    for (int j = 0; j < (N_ELEM / 4) / 64; ++j) {
        const int i = lane + j * 64;
        float4 ov = o4[i];
        float4 tv = t4[i];
        float d0 = ov.x - tv.x;
        float d1 = ov.y - tv.y;
        float d2 = ov.z - tv.z;
        float d3 = ov.w - tv.w;
        ssd0 += d0 * d0 + d1 * d1;
        ssd1 += d2 * d2 + d3 * d3;
        tmax0 = fmaxf(tmax0, fmaxf(tv.x, tv.y));
        tmax1 = fmaxf(tmax1, fmaxf(tv.z, tv.w));
        tmin0 = fminf(tmin0, fminf(tv.x, tv.y));
        tmin1 = fminf(tmin1, fminf(tv.z, tv.w));
    }
    float ssd  = ssd0 + ssd1;
    float tmax = fmaxf(tmax0, tmax1);
    float tmin = fminf(tmin0, tmin1);

    // Wave-64 butterfly reduce; all lanes end with the row result.
#pragma unroll
    for (int off = 32; off > 0; off >>= 1) {
        ssd  += __shfl_xor(ssd, off, 64);
        tmax  = fmaxf(tmax, __shfl_xor(tmax, off, 64));
        tmin  = fminf(tmin, __shfl_xor(tmin, off, 64));
    }

    const float rmse  = sqrtf(ssd * (1.0f / (float)N_ELEM));
    const float local = wgt * rmse / (tmax - tmin);

    // Per-block combine, one plain store per block.
    __shared__ float s_part[BLOCK / 64];
    if (lane == 0) s_part[wave] = local;
    __syncthreads();
    if (tid == 0) {
        partial[blockIdx.x] = s_part[0] + s_part[1] + s_part[2] + s_part[3];
    }
}

// Stage 2: one block reduces GRID1 partials and writes the final scalar.
__global__ __launch_bounds__(BLOCK)
void wnrmse_stage2(const float* __restrict__ partial, float* __restrict__ out)
{
    const int tid = threadIdx.x;
    float s = 0.0f;
    for (int i = tid; i < GRID1; i += BLOCK) s += partial[i];

#pragma unroll
    for (int off = 32; off > 0; off >>= 1) s += __shfl_xor(s, off, 64);

    __shared__ float s_part[BLOCK / 64];
    const int wave = tid >> 6;
    const int lane = tid & 63;
    if (lane == 0) s_part[wave] = s;
    __syncthreads();
    if (tid == 0) {
        float tot = s_part[0] + s_part[1] + s_part[2] + s_part[3];
        out[0] = tot * (1.0f / (float)BATCH);
    }
}

extern "C" void kernel_launch(void* const* d_in, const int* in_sizes, int n_in,
                              void* d_out, int out_size, void* d_ws, size_t ws_size,
                              hipStream_t stream) {
    const float* o1 = (const float*)d_in[0];
    const float* t1 = (const float*)d_in[1];
    const float* o2 = (const float*)d_in[2];
    const float* t2 = (const float*)d_in[3];
    const float* o3 = (const float*)d_in[4];
    const float* t3 = (const float*)d_in[5];
    float* out     = (float*)d_out;
    float* partial = (float*)d_ws;    // GRID1 floats = 12 KiB, fully overwritten

    wnrmse_stage1<<<GRID1, BLOCK, 0, stream>>>(o1, t1, o2, t2, o3, t3, partial);
    wnrmse_stage2<<<1, BLOCK, 0, stream>>>(partial, out);
}